// Round 12
// baseline (24332.991 us; speedup 1.0000x reference)
//
#include <hip/hip_runtime.h>
#include <hip/hip_bf16.h>

#define T_STEPS 256
#define BS      64
#define NTOKEN  512
#define NINP    512
#define NHID    2048
#define NB      8
#define TOPKN   4
#define BSZ     256
#define ATT_OUT 340
#define DK      64
#define NH_C    4
#define DK_C    32
#define KSUM    (ATT_OUT + BSZ)   // 596
#define KV1     (DK + ATT_OUT)    // 404
#define RV      596               // k1v1 row: [v1 0..340) [wk 340..596), wk is BSZ-dim
#define GATES   1024
#define NWG     256

#define AGENT __HIP_MEMORY_SCOPE_AGENT

__device__ __forceinline__ float sigf(float x) { return 1.0f / (1.0f + expf(-x)); }
__device__ __forceinline__ float aload(const float* p) {
  return __hip_atomic_load(p, __ATOMIC_RELAXED, AGENT);
}
__device__ __forceinline__ void astore(float* p, float v) {
  __hip_atomic_store(p, v, __ATOMIC_RELAXED, AGENT);
}
__device__ __forceinline__ unsigned aloadu(const unsigned* p) {
  return __hip_atomic_load(p, __ATOMIC_RELAXED, AGENT);
}
__device__ __forceinline__ void astoreu(unsigned* p, unsigned v) {
  __hip_atomic_store(p, v, __ATOMIC_RELAXED, AGENT);
}

__device__ __forceinline__ void gfma(float4& acc, const float4& a4, const float4& w0,
                                     const float4& w1, const float4& w2, const float4& w3) {
  acc.x += a4.x * w0.x + a4.y * w1.x + a4.z * w2.x + a4.w * w3.x;
  acc.y += a4.x * w0.y + a4.y * w1.y + a4.z * w2.y + a4.w * w3.y;
  acc.z += a4.x * w0.z + a4.y * w1.z + a4.z * w2.z + a4.w * w3.z;
  acc.w += a4.x * w0.w + a4.y * w1.w + a4.z * w2.w + a4.w * w3.w;
}
__device__ __forceinline__ void sfma(float4& acc, float s, const float4& w) {
  acc.x += s * w.x; acc.y += s * w.y; acc.z += s * w.z; acc.w += s * w.w;
}

// Distributed-arrival grid barrier; per-WG gen lines (zero-contention release).
__device__ __forceinline__ void gbar(unsigned* flags, unsigned* gen, unsigned e) {
  const int w = blockIdx.x, tid = threadIdx.x;
  asm volatile("s_waitcnt vmcnt(0) lgkmcnt(0)" ::: "memory");
  __syncthreads();
  if (tid == 0) astoreu(&flags[w * 16], e);
  if (w == NWG - 1) {
    if (tid < NWG) {
      while (aloadu(&flags[tid * 16]) < e) __builtin_amdgcn_s_sleep(1);
    }
    __syncthreads();
    if (tid < NWG) astoreu(&gen[tid * 16], e);
  } else {
    if (tid == 0) {
      while (aloadu(&gen[w * 16]) < e) __builtin_amdgcn_s_sleep(1);
    }
  }
  __syncthreads();
}

// ---------- Precompute 1: Wc = W_enc @ [Wk | Wv], bias_kv = b_enc @ [Wk|Wv]
__global__ void k_wc(const float* __restrict__ W_enc, const float* __restrict__ b_enc,
                     const float* __restrict__ Wk, const float* __restrict__ Wv,
                     float* __restrict__ Wc, float* __restrict__ bias_kv) {
  __shared__ float row[NINP];
  int d = blockIdx.x;
  const float* src = (d < NTOKEN) ? (W_enc + (size_t)d * NINP) : b_enc;
  for (int i = threadIdx.x; i < NINP; i += blockDim.x) row[i] = src[i];
  __syncthreads();
  float* dst = (d < NTOKEN) ? (Wc + (size_t)d * KV1) : bias_kv;
  for (int j = threadIdx.x; j < KV1; j += blockDim.x) {
    float acc = 0.f;
    if (j < DK) {
      for (int p = 0; p < NINP; ++p) acc += row[p] * Wk[(size_t)p * DK + j];
    } else {
      int jj = j - DK;
      for (int p = 0; p < NINP; ++p) acc += row[p] * Wv[(size_t)p * ATT_OUT + jj];
    }
    dst[j] = acc;
  }
}

// ---------- Precompute 2: k1v1[t,b] = [v1 | wk],  wk = Wq @ k1 (BSZ=256 components)
__global__ void k_kv(const float* __restrict__ x, const float* __restrict__ Wc,
                     const float* __restrict__ bias_kv, const float* __restrict__ Wq,
                     float* __restrict__ k1v1) {
  __shared__ float xl[8 * NTOKEN];
  __shared__ float k1s[8 * DK];
  int r0 = blockIdx.x * 8;
  for (int i = threadIdx.x; i < 8 * NTOKEN; i += blockDim.x)
    xl[i] = x[(size_t)r0 * NTOKEN + i];
  __syncthreads();
  for (int j = threadIdx.x; j < KV1; j += 256) {
    float bj = bias_kv[j];
    float acc[8];
#pragma unroll
    for (int r = 0; r < 8; ++r) acc[r] = bj;
    for (int d = 0; d < NTOKEN; ++d) {
      float wc = Wc[(size_t)d * KV1 + j];
#pragma unroll
      for (int r = 0; r < 8; ++r) acc[r] += xl[r * NTOKEN + d] * wc;
    }
    if (j < DK) {
#pragma unroll
      for (int r = 0; r < 8; ++r) k1s[r * DK + j] = acc[r];
    } else {
#pragma unroll
      for (int r = 0; r < 8; ++r) k1v1[(size_t)(r0 + r) * RV + (j - DK)] = acc[r];
    }
  }
  __syncthreads();
  {  // wk[r][d] = sum_dk k1[r][dk] * Wq[d][dk],  d = threadIdx.x in [0,256)
    int d = threadIdx.x;
    float a[8];
#pragma unroll
    for (int r = 0; r < 8; ++r) a[r] = 0.f;
    for (int dk4 = 0; dk4 < 16; ++dk4) {
      float4 w4 = *(const float4*)&Wq[(size_t)d * DK + dk4 * 4];
#pragma unroll
      for (int r = 0; r < 8; ++r) {
        float4 kk = *(const float4*)&k1s[r * DK + dk4 * 4];
        a[r] += kk.x * w4.x + kk.y * w4.y + kk.z * w4.z + kk.w * w4.w;
      }
    }
#pragma unroll
    for (int r = 0; r < 8; ++r) k1v1[(size_t)(r0 + r) * RV + ATT_OUT + d] = a[r];
  }
}

// ---------- Precompute 3: gate-interleaved fused weights
__global__ void k_fuse(const float* __restrict__ Wi, const float* __restrict__ Wh,
                       const float* __restrict__ b_lstm,
                       float* __restrict__ Wf, float* __restrict__ bf) {
  int nk = blockIdx.x;  // 8*596
  int n = nk / KSUM, k = nk % KSUM;
  const float* src = (k < ATT_OUT) ? (Wi + ((size_t)n * ATT_OUT + k) * GATES)
                                   : (Wh + ((size_t)n * BSZ + (k - ATT_OUT)) * GATES);
  float* dst = Wf + ((size_t)n * KSUM + k) * GATES;
  for (int gc = threadIdx.x; gc < GATES; gc += blockDim.x) {
    int t = gc >> 8, j = gc & 255;
    dst[j * 4 + t] = src[gc];
  }
  if (k == 0) {
    for (int gc = threadIdx.x; gc < GATES; gc += blockDim.x) {
      int t = gc >> 8, j = gc & 255;
      bf[(size_t)n * GATES + j * 4 + t] = b_lstm[(size_t)n * GATES + gc];
    }
  }
}

// ---------- Main persistent RNN kernel: 256 WGs x 1024 threads
// GEMM = R6-proven acc[4] shape: thread (kh8, bo4, jj32) -> 4 batches x 4 gates,
// K interleaved 8-way (no spills at the 64-VGPR cap). 2-pass deterministic
// reduction. All cross-phase state (wk/v1/bias) LDS-resident.
// LDS (floats): c_cur[512]@0 c_pend[512]@512 zl[128]@1024 attl[16]@1152
//   bfl[128]@1168  h_comm[2048]@1296  kvl[16*596]@3344  hl[16*256]@12880
//   R1[6736]@16976.  red4 (float4) overlays hl+R1 (dead span) during S4.
__global__ __launch_bounds__(1024)
void k_rnn(const float* __restrict__ k1v1, const float* __restrict__ Wf,
           const float* __restrict__ bf,
           const float* __restrict__ Wq_c, const float* __restrict__ Wk_c,
           const float* __restrict__ Wv_c, const float* __restrict__ Wo_c,
           const float* __restrict__ c0,
           float* h, float* hnew, float* zbuf,
           unsigned* bar, float* __restrict__ out) {
  const int w   = blockIdx.x;       // w = bg*64 + csg*8 + n
  const int tid = threadIdx.x;      // 1024
  const int n   = w & 7;            // block -> XCD, Wf[n] L2-resident
  const int csg = (w >> 3) & 7;     // 32-cell slice
  const int bg  = w >> 6;           // batch group of 16
  const int jjG = tid & 31, boG = (tid >> 5) & 3, khG = tid >> 7;  // acc[4] mapping
  const int bb  = tid >> 6, lane = tid & 63;   // staging roles

  unsigned* flags = bar;
  unsigned* gen   = bar + 4096;

  __shared__ __align__(16) float smem[23712];
  float* c_cur  = smem;            // [16][32]
  float* c_pend = smem + 512;      // [16][32]
  float* zl     = smem + 1024;     // [16][8]
  float* attl   = smem + 1152;     // [16]
  float* bfl    = smem + 1168;     // [128] gate-interleaved bias slice
  float* h_comm = smem + 1296;     // [2048] (w<64 only)
  float* kvl    = smem + 3344;     // [16][596] : [0,340)=v1, [340,596)=wk
  float* hl     = smem + 12880;    // [16][256]
  float* R1     = smem + 16976;    // 6736 (B-phase scratch)
  float4* red4  = (float4*)(smem + 12880);  // overlays hl+R1 (10832 floats)

  // ===== init =====
  if (tid < 512)
    c_cur[tid] = c0[(size_t)(bg * 16 + (tid >> 5)) * NHID + n * BSZ + csg * 32 + (tid & 31)];
  if (tid < 128) bfl[tid] = bf[(size_t)n * GATES + csg * 128 + tid];
  if (w < BS) {
#pragma unroll
    for (int r = 0; r < 2; ++r) {
      int i = r * 1024 + tid;
      h_comm[i] = aload(&h[(size_t)w * NHID + i]);
    }
  }
  for (int i = tid; i < 2384; i += 1024) {  // kvl <- [v1|wk](t=0), 2384 = 16*596/4
    int b = i / 149, q = i - b * 149;
    *(float4*)&kvl[b * 596 + q * 4] =
        *(const float4*)&k1v1[((size_t)(bg * 16 + b)) * RV + q * 4];
  }
  __syncthreads();

  for (int t = 0; t < T_STEPS; ++t) {
    float* zwr = zbuf + (t & 1) * 512;        // z(t)
    float* zrd = zbuf + ((t & 1) ^ 1) * 512;  // z(t-1)

    // ===== S1: stage h -> hl; z = h.wk (wk from LDS); zl <- z(t-1) =====
    if (tid < 128) zl[tid] = aload(&zrd[(bg * 16 + (tid >> 3)) * 8 + (tid & 7)]);
    {
      const float* hp = &h[(size_t)(bg * 16 + bb) * NHID + n * BSZ + lane * 4];
      float4 h4;
      h4.x = aload(hp); h4.y = aload(hp + 1); h4.z = aload(hp + 2); h4.w = aload(hp + 3);
      *(float4*)&hl[bb * 256 + lane * 4] = h4;
      float4 wk4 = *(const float4*)&kvl[bb * 596 + ATT_OUT + lane * 4];
      float zp = h4.x * wk4.x + h4.y * wk4.y + h4.z * wk4.z + h4.w * wk4.w;
      zp += __shfl_xor(zp, 1);  zp += __shfl_xor(zp, 2);  zp += __shfl_xor(zp, 4);
      zp += __shfl_xor(zp, 8);  zp += __shfl_xor(zp, 16); zp += __shfl_xor(zp, 32);
      if (lane == 0) {
        float z = zp * 0.125f;
        attl[bb] = sigf(z);
        if (csg == 0) astore(&zwr[(bg * 16 + bb) * 8 + n], z);
      }
    }
    __syncthreads();

    // ===== S2: scale v1 part of kvl by att1 (in place) =====
    for (int i = tid; i < 1360; i += 1024) {
      int b = i / 85, q = i - b * 85;
      float a = attl[b];
      float4 v = *(float4*)&kvl[b * 596 + q * 4];
      v.x *= a; v.y *= a; v.z *= a; v.w *= a;
      *(float4*)&kvl[b * 596 + q * 4] = v;
    }
    __syncthreads();

    // ===== S3: GEMM — thread (khG8, boG4, jjG32): 4 batches x 4 gates =====
    float4 acc[4];
#pragma unroll
    for (int i = 0; i < 4; ++i) acc[i] = make_float4(0.f, 0.f, 0.f, 0.f);
    {
      const float* Wr = Wf + (size_t)n * KSUM * GATES + (size_t)(csg * 32 + jjG) * 4;
      const int bbase = boG * 4;
#pragma unroll 4
      for (int k4 = khG * 4; k4 < KSUM; k4 += 32) {
        const float* wp = Wr + (size_t)k4 * GATES;
        float4 w0 = *(const float4*)(wp);
        float4 w1 = *(const float4*)(wp + GATES);
        float4 w2 = *(const float4*)(wp + 2 * GATES);
        float4 w3 = *(const float4*)(wp + 3 * GATES);
        if (k4 < ATT_OUT) {
#pragma unroll
          for (int i = 0; i < 4; ++i) {
            float4 a4 = *(const float4*)&kvl[(bbase + i) * 596 + k4];
            gfma(acc[i], a4, w0, w1, w2, w3);
          }
        } else {
#pragma unroll
          for (int i = 0; i < 4; ++i) {
            float4 a4 = *(const float4*)&hl[(bbase + i) * 256 + (k4 - ATT_OUT)];
            gfma(acc[i], a4, w0, w1, w2, w3);
          }
        }
      }
    }
    __syncthreads();  // kvl/hl reads done; hl+R1 reusable as red4

    // ===== S4: deterministic 2-pass kh-reduction + LSTM + lazy c-commit =====
    // red4 stride 260 float4 per khG; pass p covers batches with (batch&3) in {2p,2p+1}
#pragma unroll
    for (int p = 0; p < 2; ++p) {
      red4[khG * 260 + boG * 64 + 0 * 32 + jjG] = acc[2 * p + 0];
      red4[khG * 260 + boG * 64 + 1 * 32 + jjG] = acc[2 * p + 1];
      __syncthreads();
      if (tid < 256) {
        const int rb = tid >> 5, jjr = tid & 31;
        const int bo_r = rb >> 1, q_r = rb & 1;
        const int batch = bo_r * 4 + 2 * p + q_r;
        float4 g4 = make_float4(0.f, 0.f, 0.f, 0.f);
#pragma unroll
        for (int kh = 0; kh < 8; ++kh) {   // fixed order -> deterministic
          float4 v = red4[kh * 260 + bo_r * 64 + q_r * 32 + jjr];
          g4.x += v.x; g4.y += v.y; g4.z += v.z; g4.w += v.w;
        }
        const int jgr = csg * 32 + jjr;
        float4 bia = *(const float4*)&bfl[jjr * 4];
        float ig = sigf(g4.x + bia.x), fg = sigf(g4.y + bia.y);
        float gg = tanhf(g4.z + bia.z), og = sigf(g4.w + bia.w);
        float cc = c_cur[batch * 32 + jjr];
        if (t > 0) {
          float zn = zl[batch * 8 + n];
          int rank = 0;
#pragma unroll
          for (int j = 0; j < NB; ++j) {
            float zj = zl[batch * 8 + j];
            rank += (zj > zn || (zj == zn && j < n)) ? 1 : 0;
          }
          if (rank < TOPKN) cc = c_pend[batch * 32 + jjr];
        }
        float cn = fg * cc + ig * gg;
        float hn = og * tanhf(cn);
        c_cur[batch * 32 + jjr]  = cc;
        c_pend[batch * 32 + jjr] = cn;
        astore(&hnew[(size_t)(bg * 16 + batch) * NHID + n * BSZ + jgr], hn);
      }
      __syncthreads();
    }
    // refill kvl <- [v1|wk](t+1) directly global->LDS (drained at gbar)
    {
      const int tn = (t + 1 < T_STEPS) ? t + 1 : t;
      for (int i = tid; i < 2384; i += 1024) {
        int b = i / 149, q = i - b * 149;
        *(float4*)&kvl[b * 596 + q * 4] =
            *(const float4*)&k1v1[((size_t)tn * BS + bg * 16 + b) * RV + q * 4];
      }
    }
    gbar(flags, gen, 2u * t + 1u);

    // ===== PHASE B (WGs 0..63, one batch each) =====
    if (w < BS) {
      const int b = w;
      float* hnewl = R1;           // 2048
      float* qcl   = R1 + 2048;    // 8 x 132
      float* kcl   = R1 + 3104;    // 8 x 132
      float* vcl   = R1 + 4160;    // 8 x 128
      float* ocl   = R1 + 5184;    // 8 x 128
      float* scl   = R1 + 6208;    // [4][8][8]
      float* acl   = R1 + 6464;    // [4][8][8]
      float* zlB   = R1 + 6720;    // 8

#pragma unroll
      for (int r = 0; r < 2; ++r) {
        int i = r * 1024 + tid;
        hnewl[i] = aload(&hnew[(size_t)b * NHID + i]);
      }
      if (tid < 8) zlB[tid] = aload(&zwr[b * 8 + tid]);
      __syncthreads();
      // qkv: tid<768 : (mat3, c4 32, kq 8) -> 8 nn accumulators, kq shfl-reduce
      if (tid < 768) {
        int mat = tid >> 8, c4 = (tid >> 3) & 31, kq = tid & 7;
        int c0 = c4 * 4;
        const float* W = (mat == 0) ? Wq_c : (mat == 1) ? Wk_c : Wv_c;
        float4 a8[8];
#pragma unroll
        for (int i = 0; i < 8; ++i) a8[i] = make_float4(0.f, 0.f, 0.f, 0.f);
#pragma unroll 2
        for (int m = 0; m < 8; ++m) {
          int d0 = kq * 4 + 32 * m;
          float4 w_0 = *(const float4*)&W[(size_t)(d0 + 0) * 128 + c0];
          float4 w_1 = *(const float4*)&W[(size_t)(d0 + 1) * 128 + c0];
          float4 w_2 = *(const float4*)&W[(size_t)(d0 + 2) * 128 + c0];
          float4 w_3 = *(const float4*)&W[(size_t)(d0 + 3) * 128 + c0];
#pragma unroll
          for (int nn = 0; nn < 8; ++nn) {
            float4 h4 = *(const float4*)&hnewl[nn * 256 + d0];
            sfma(a8[nn], h4.x, w_0); sfma(a8[nn], h4.y, w_1);
            sfma(a8[nn], h4.z, w_2); sfma(a8[nn], h4.w, w_3);
          }
        }
#pragma unroll
        for (int mk = 1; mk <= 4; mk <<= 1) {
#pragma unroll
          for (int nn = 0; nn < 8; ++nn) {
            a8[nn].x += __shfl_xor(a8[nn].x, mk);
            a8[nn].y += __shfl_xor(a8[nn].y, mk);
            a8[nn].z += __shfl_xor(a8[nn].z, mk);
            a8[nn].w += __shfl_xor(a8[nn].w, mk);
          }
        }
        if (kq == 0) {
          if (mat == 2) {
#pragma unroll
            for (int nn = 0; nn < 8; ++nn) *(float4*)&vcl[nn * 128 + c0] = a8[nn];
          } else {
            float* dst = (mat == 0) ? qcl : kcl;
#pragma unroll
            for (int nn = 0; nn < 8; ++nn) *(float4*)&dst[nn * 132 + c0] = a8[nn];
          }
        }
      }
      __syncthreads();
      // scores: tid<256 : (hh, nq, m) dot32 — 132-stride rows are conflict-free
      if (tid < 256) {
        int hh = tid >> 6, nq = (tid >> 3) & 7, m = tid & 7;
        const float* qrow = &qcl[nq * 132 + hh * 32];
        const float* krow = &kcl[m * 132 + hh * 32];
        float a = 0.f;
#pragma unroll
        for (int k4 = 0; k4 < 8; ++k4) {
          float4 q4 = *(const float4*)&qrow[k4 * 4];
          float4 kv = *(const float4*)&krow[k4 * 4];
          a += q4.x * kv.x + q4.y * kv.y + q4.z * kv.z + q4.w * kv.w;
        }
        scl[tid] = a * 0.17677669529663687f;
      }
      __syncthreads();
      if (tid < 32) {  // softmax rows
        int hh = tid >> 3, nq = tid & 7;
        const float* row = &scl[hh * 64 + nq * 8];
        float mx = -1e30f;
#pragma unroll
        for (int m = 0; m < NB; ++m) mx = fmaxf(mx, row[m]);
        float e[NB]; float sum = 0.f;
#pragma unroll
        for (int m = 0; m < NB; ++m) { e[m] = expf(row[m] - mx); sum += e[m]; }
        float inv = 1.f / sum;
#pragma unroll
        for (int m = 0; m < NB; ++m) acl[(hh * 8 + nq) * 8 + m] = e[m] * inv;
      }
      __syncthreads();
      if (tid < 256) {  // oc = ac @ vc
        int nn = tid >> 5, c4 = tid & 31, c0 = c4 * 4, hh = c4 >> 3;
        const float* arow = &acl[(hh * 8 + nn) * 8];
        float4 a4 = make_float4(0.f, 0.f, 0.f, 0.f);
#pragma unroll
        for (int m = 0; m < NB; ++m) {
          float a = arow[m];
          float4 v4 = *(const float4*)&vcl[m * 128 + c0];
          sfma(a4, a, v4);
        }
        *(float4*)&ocl[tid * 4] = a4;
      }
      __syncthreads();
      if (tid < 512) {  // commit h (h_comm + global h for masked) + out
        int nn = tid >> 6, j0 = (tid & 63) * 4;
        int li = nn * BSZ + j0;
        float zn = zlB[nn];
        int rank = 0;
#pragma unroll
        for (int j = 0; j < NB; ++j) {
          float zj = zlB[j];
          rank += (zj > zn || (zj == zn && j < nn)) ? 1 : 0;
        }
        float4 hv4;
        if (rank < TOPKN) {
          const float* oc = &ocl[nn * 128];
          float4 add = make_float4(0.f, 0.f, 0.f, 0.f);
#pragma unroll 4
          for (int p = 0; p < 128; ++p) {
            float o = oc[p];
            float4 w4 = *(const float4*)&Wo_c[(size_t)p * BSZ + j0];
            sfma(add, o, w4);
          }
          hv4.x = hnewl[li] + add.x;     hv4.y = hnewl[li + 1] + add.y;
          hv4.z = hnewl[li + 2] + add.z; hv4.w = hnewl[li + 3] + add.w;
          *(float4*)&h_comm[li] = hv4;
          size_t base = (size_t)b * NHID + li;
          astore(&h[base], hv4.x);     astore(&h[base + 1], hv4.y);
          astore(&h[base + 2], hv4.z); astore(&h[base + 3], hv4.w);
        } else {
          hv4 = *(float4*)&h_comm[li];
        }
        *(float4*)&out[((size_t)t * BS + b) * NHID + li] = hv4;
      }
    }
    gbar(flags, gen, 2u * t + 2u);
  }
}

__global__ void k_sentinel(float* out) { out[0] = 12345.0f; }

extern "C" void kernel_launch(void* const* d_in, const int* in_sizes, int n_in,
                              void* d_out, int out_size, void* d_ws, size_t ws_size,
                              hipStream_t stream) {
  (void)in_sizes; (void)n_in; (void)out_size;
  const float* x      = (const float*)d_in[0];
  const float* h0     = (const float*)d_in[1];
  const float* c0     = (const float*)d_in[2];
  const float* W_enc  = (const float*)d_in[3];
  const float* b_enc  = (const float*)d_in[4];
  const float* Wq     = (const float*)d_in[5];
  const float* Wk     = (const float*)d_in[6];
  const float* Wv     = (const float*)d_in[7];
  const float* Wi     = (const float*)d_in[8];
  const float* Wh     = (const float*)d_in[9];
  const float* b_lstm = (const float*)d_in[10];
  const float* Wq_c   = (const float*)d_in[11];
  const float* Wk_c   = (const float*)d_in[12];
  const float* Wv_c   = (const float*)d_in[13];
  const float* Wo_c   = (const float*)d_in[14];
  float* out = (float*)d_out;

  float* ws = (float*)d_ws;
  size_t off = 0;
  auto alloc = [&](size_t nf) { float* p = ws + off; off += (nf + 15) & ~(size_t)15; return p; };
  float* k1v1 = alloc((size_t)T_STEPS * BS * RV);
  float* Wc   = alloc((size_t)NTOKEN * KV1);
  float* bias = alloc(KV1);
  float* Wf   = alloc((size_t)NB * KSUM * GATES);
  float* bf   = alloc((size_t)NB * GATES);
  float* h    = alloc((size_t)BS * NHID);
  float* hnew = alloc((size_t)BS * NHID);
  float* zbuf = alloc(2 * (size_t)BS * NB);
  // barrier: 256 flag lines + 256 gen lines (16 u32 each)
  unsigned* bar = (unsigned*)(ws + off); off += 8192 + 16;

  if (ws_size < off * sizeof(float)) {  // loud failure instead of OOB corruption
    hipLaunchKernelGGL(k_sentinel, dim3(1), dim3(1), 0, stream, out);
    return;
  }

  hipMemsetAsync(bar, 0, 8192 * sizeof(unsigned), stream);
  hipMemcpyAsync(h, h0, (size_t)BS * NHID * sizeof(float), hipMemcpyDeviceToDevice, stream);

  hipLaunchKernelGGL(k_wc,   dim3(NTOKEN + 1),       dim3(128), 0, stream, W_enc, b_enc, Wk, Wv, Wc, bias);
  hipLaunchKernelGGL(k_kv,   dim3(T_STEPS * BS / 8), dim3(256), 0, stream, x, Wc, bias, Wq, k1v1);
  hipLaunchKernelGGL(k_fuse, dim3(NB * KSUM),        dim3(256), 0, stream, Wi, Wh, b_lstm, Wf, bf);
  hipLaunchKernelGGL(k_rnn,  dim3(NWG),              dim3(1024), 0, stream,
                     k1v1, Wf, bf, Wq_c, Wk_c, Wv_c, Wo_c, c0,
                     h, hnew, zbuf, bar, out);
}

// Round 13
// 19348.277 us; speedup vs baseline: 1.2576x; 1.2576x over previous
//
#include <hip/hip_runtime.h>
#include <hip/hip_bf16.h>

#define T_STEPS 256
#define BS      64
#define NTOKEN  512
#define NINP    512
#define NHID    2048
#define NB      8
#define TOPKN   4
#define BSZ     256
#define ATT_OUT 340
#define DK      64
#define NH_C    4
#define DK_C    32
#define KSUM    (ATT_OUT + BSZ)   // 596
#define KV1     (DK + ATT_OUT)    // 404
#define RV      596               // k1v1 row: [v1 0..340) [wk 340..596), wk is BSZ-dim
#define GATES   1024
#define NWG     256

#define AGENT __HIP_MEMORY_SCOPE_AGENT

__device__ __forceinline__ float sigf(float x) { return 1.0f / (1.0f + expf(-x)); }
__device__ __forceinline__ float aload(const float* p) {
  return __hip_atomic_load(p, __ATOMIC_RELAXED, AGENT);
}
__device__ __forceinline__ void astore(float* p, float v) {
  __hip_atomic_store(p, v, __ATOMIC_RELAXED, AGENT);
}
__device__ __forceinline__ unsigned aloadu(const unsigned* p) {
  return __hip_atomic_load(p, __ATOMIC_RELAXED, AGENT);
}
__device__ __forceinline__ void astoreu(unsigned* p, unsigned v) {
  __hip_atomic_store(p, v, __ATOMIC_RELAXED, AGENT);
}

__device__ __forceinline__ void gfma(float4& acc, const float4& a4, const float4& w0,
                                     const float4& w1, const float4& w2, const float4& w3) {
  acc.x += a4.x * w0.x + a4.y * w1.x + a4.z * w2.x + a4.w * w3.x;
  acc.y += a4.x * w0.y + a4.y * w1.y + a4.z * w2.y + a4.w * w3.y;
  acc.z += a4.x * w0.z + a4.y * w1.z + a4.z * w2.z + a4.w * w3.z;
  acc.w += a4.x * w0.w + a4.y * w1.w + a4.z * w2.w + a4.w * w3.w;
}
__device__ __forceinline__ void sfma(float4& acc, float s, const float4& w) {
  acc.x += s * w.x; acc.y += s * w.y; acc.z += s * w.z; acc.w += s * w.w;
}

// Distributed-arrival grid barrier; per-WG gen lines (zero-contention release).
__device__ __forceinline__ void gbar(unsigned* flags, unsigned* gen, unsigned e) {
  const int w = blockIdx.x, tid = threadIdx.x;
  asm volatile("s_waitcnt vmcnt(0) lgkmcnt(0)" ::: "memory");
  __syncthreads();
  if (tid == 0) astoreu(&flags[w * 16], e);
  if (w == NWG - 1) {
    if (tid < NWG) {
      while (aloadu(&flags[tid * 16]) < e) __builtin_amdgcn_s_sleep(1);
    }
    __syncthreads();
    if (tid < NWG) astoreu(&gen[tid * 16], e);
  } else {
    if (tid == 0) {
      while (aloadu(&gen[w * 16]) < e) __builtin_amdgcn_s_sleep(1);
    }
  }
  __syncthreads();
}

// ---------- Precompute 1: Wc = W_enc @ [Wk | Wv], bias_kv = b_enc @ [Wk|Wv]
__global__ void k_wc(const float* __restrict__ W_enc, const float* __restrict__ b_enc,
                     const float* __restrict__ Wk, const float* __restrict__ Wv,
                     float* __restrict__ Wc, float* __restrict__ bias_kv) {
  __shared__ float row[NINP];
  int d = blockIdx.x;
  const float* src = (d < NTOKEN) ? (W_enc + (size_t)d * NINP) : b_enc;
  for (int i = threadIdx.x; i < NINP; i += blockDim.x) row[i] = src[i];
  __syncthreads();
  float* dst = (d < NTOKEN) ? (Wc + (size_t)d * KV1) : bias_kv;
  for (int j = threadIdx.x; j < KV1; j += blockDim.x) {
    float acc = 0.f;
    if (j < DK) {
      for (int p = 0; p < NINP; ++p) acc += row[p] * Wk[(size_t)p * DK + j];
    } else {
      int jj = j - DK;
      for (int p = 0; p < NINP; ++p) acc += row[p] * Wv[(size_t)p * ATT_OUT + jj];
    }
    dst[j] = acc;
  }
}

// ---------- Precompute 2: k1v1[t,b] = [v1 | wk],  wk = Wq @ k1 (BSZ components)
__global__ void k_kv(const float* __restrict__ x, const float* __restrict__ Wc,
                     const float* __restrict__ bias_kv, const float* __restrict__ Wq,
                     float* __restrict__ k1v1) {
  __shared__ float xl[8 * NTOKEN];
  __shared__ float k1s[8 * DK];
  int r0 = blockIdx.x * 8;
  for (int i = threadIdx.x; i < 8 * NTOKEN; i += blockDim.x)
    xl[i] = x[(size_t)r0 * NTOKEN + i];
  __syncthreads();
  for (int j = threadIdx.x; j < KV1; j += 256) {
    float bj = bias_kv[j];
    float acc[8];
#pragma unroll
    for (int r = 0; r < 8; ++r) acc[r] = bj;
    for (int d = 0; d < NTOKEN; ++d) {
      float wc = Wc[(size_t)d * KV1 + j];
#pragma unroll
      for (int r = 0; r < 8; ++r) acc[r] += xl[r * NTOKEN + d] * wc;
    }
    if (j < DK) {
#pragma unroll
      for (int r = 0; r < 8; ++r) k1s[r * DK + j] = acc[r];
    } else {
#pragma unroll
      for (int r = 0; r < 8; ++r) k1v1[(size_t)(r0 + r) * RV + (j - DK)] = acc[r];
    }
  }
  __syncthreads();
  {  // wk[r][d] = sum_dk k1[r][dk] * Wq[d][dk],  d = threadIdx.x in [0,256)
    int d = threadIdx.x;
    float a[8];
#pragma unroll
    for (int r = 0; r < 8; ++r) a[r] = 0.f;
    for (int dk4 = 0; dk4 < 16; ++dk4) {
      float4 w4 = *(const float4*)&Wq[(size_t)d * DK + dk4 * 4];
#pragma unroll
      for (int r = 0; r < 8; ++r) {
        float4 kk = *(const float4*)&k1s[r * DK + dk4 * 4];
        a[r] += kk.x * w4.x + kk.y * w4.y + kk.z * w4.z + kk.w * w4.w;
      }
    }
#pragma unroll
    for (int r = 0; r < 8; ++r) k1v1[(size_t)(r0 + r) * RV + ATT_OUT + d] = a[r];
  }
}

// ---------- Precompute 3: gate-interleaved fused weights
__global__ void k_fuse(const float* __restrict__ Wi, const float* __restrict__ Wh,
                       const float* __restrict__ b_lstm,
                       float* __restrict__ Wf, float* __restrict__ bf) {
  int nk = blockIdx.x;  // 8*596
  int n = nk / KSUM, k = nk % KSUM;
  const float* src = (k < ATT_OUT) ? (Wi + ((size_t)n * ATT_OUT + k) * GATES)
                                   : (Wh + ((size_t)n * BSZ + (k - ATT_OUT)) * GATES);
  float* dst = Wf + ((size_t)n * KSUM + k) * GATES;
  for (int gc = threadIdx.x; gc < GATES; gc += blockDim.x) {
    int t = gc >> 8, j = gc & 255;
    dst[j * 4 + t] = src[gc];
  }
  if (k == 0) {
    for (int gc = threadIdx.x; gc < GATES; gc += blockDim.x) {
      int t = gc >> 8, j = gc & 255;
      bf[(size_t)n * GATES + j * 4 + t] = b_lstm[(size_t)n * GATES + gc];
    }
  }
}

// ---------- Main persistent RNN kernel: 256 WGs x 1024 threads
// Round-6-proven structure: unified Al[16][600] (no branch in K-loop -> no
// spills at the 64-VGPR cap), acc[8] GEMM (kh16, bo2, jj32), 4-pass
// deterministic reduction, LDS c-state + rank commit.  Diffs vs round-6:
// (1) zbuf ping-pong (race fix), (2) per-WG gen-line barrier release.
// LDS (floats): c_cur[512]@0 c_pend[512]@512 zl[128]@1024 attl[16]@1152
//   h_comm[2048]@1168  Al[16][600]@3216.  red4/B-phase overlay dead Al.
__global__ __launch_bounds__(1024)
void k_rnn(const float* __restrict__ k1v1, const float* __restrict__ Wf,
           const float* __restrict__ bf,
           const float* __restrict__ Wq_c, const float* __restrict__ Wk_c,
           const float* __restrict__ Wv_c, const float* __restrict__ Wo_c,
           const float* __restrict__ c0,
           float* h, float* hnew, float* zbuf,
           unsigned* bar, float* __restrict__ out) {
  const int w   = blockIdx.x;       // w = bg*64 + csg*8 + n
  const int tid = threadIdx.x;      // 1024
  const int n   = w & 7;            // block -> XCD, Wf[n] L2-resident
  const int csg = (w >> 3) & 7;     // 32-cell slice
  const int bg  = w >> 6;           // batch group of 16
  const int jjG = tid & 31, boG = (tid >> 5) & 1, khG = tid >> 6;
  const int bb  = tid >> 6, lane = tid & 63;   // staging roles

  unsigned* flags = bar;
  unsigned* gen   = bar + 4096;

  __shared__ __align__(16) float smem[12816];
  float* c_cur  = smem;            // [16][32]
  float* c_pend = smem + 512;      // [16][32]
  float* zl     = smem + 1024;     // [16][8]
  float* attl   = smem + 1152;     // [16]
  float* h_comm = smem + 1168;     // [2048] (w<64 only)
  float* Al     = smem + 3216;     // [16][600]: [0,340)=att*v1, [340,596)=h

  // ===== init =====
  if (tid < 512)
    c_cur[tid] = c0[(size_t)(bg * 16 + (tid >> 5)) * NHID + n * BSZ + csg * 32 + (tid & 31)];
  if (w < BS) {
#pragma unroll
    for (int r = 0; r < 2; ++r) {
      int i = r * 1024 + tid;
      h_comm[i] = aload(&h[(size_t)w * NHID + i]);
    }
  }

  for (int t = 0; t < T_STEPS; ++t) {
    float* zwr = zbuf + (t & 1) * 512;        // z(t)
    float* zrd = zbuf + ((t & 1) ^ 1) * 512;  // z(t-1)

    // ===== S1: stage committed h -> Al rows [340,596); zl <- z(t-1) =====
#pragma unroll
    for (int r = 0; r < 4; ++r) {
      int i = r * 1024 + tid;
      int bb2 = i >> 8, d = i & 255;
      Al[bb2 * 600 + ATT_OUT + d] = aload(&h[(size_t)(bg * 16 + bb2) * NHID + n * BSZ + d]);
    }
    if (tid >= 512 && tid < 640) {
      int q = tid - 512;
      zl[q] = aload(&zrd[(bg * 16 + (q >> 3)) * 8 + (q & 7)]);
    }
    __syncthreads();
    // ===== S2: z = (h . wk)/8 per (batch=wave) =====
    {
      float4 h4  = *(float4*)&Al[bb * 600 + ATT_OUT + lane * 4];
      float4 wk4 = *(const float4*)&k1v1[((size_t)t * BS + bg * 16 + bb) * RV + ATT_OUT + lane * 4];
      float zp = h4.x * wk4.x + h4.y * wk4.y + h4.z * wk4.z + h4.w * wk4.w;
      zp += __shfl_xor(zp, 1);  zp += __shfl_xor(zp, 2);  zp += __shfl_xor(zp, 4);
      zp += __shfl_xor(zp, 8);  zp += __shfl_xor(zp, 16); zp += __shfl_xor(zp, 32);
      if (lane == 0) {
        float z = zp * 0.125f;
        attl[bb] = sigf(z);
        if (csg == 0) astore(&zwr[(bg * 16 + bb) * 8 + n], z);
      }
    }
    __syncthreads();
    // ===== S3: Al rows [0,340) = att1 * v1 (fresh global read) =====
    for (int i = tid; i < 16 * 85; i += 1024) {
      int b2 = i / 85, q = i - b2 * 85;
      float4 v4 = *(const float4*)&k1v1[((size_t)t * BS + bg * 16 + b2) * RV + q * 4];
      float a = attl[b2];
      float4 r;
      r.x = a * v4.x; r.y = a * v4.y; r.z = a * v4.z; r.w = a * v4.w;
      *(float4*)&Al[b2 * 600 + q * 4] = r;
    }
    __syncthreads();

    // ===== S4: GEMM — thread (khG16, boG2, jjG32): 8 batches x 4 gates =====
    float4 acc[8];
#pragma unroll
    for (int i = 0; i < 8; ++i) acc[i] = make_float4(0.f, 0.f, 0.f, 0.f);
    {
      const float* Wr = Wf + (size_t)n * KSUM * GATES + (size_t)(csg * 32 + jjG) * 4;
      const float* Ab = Al + boG * 8 * 600;
#pragma unroll 2
      for (int k4 = khG * 4; k4 < KSUM; k4 += 64) {
        const float* wp = Wr + (size_t)k4 * GATES;
        float4 w0 = *(const float4*)(wp);
        float4 w1 = *(const float4*)(wp + GATES);
        float4 w2 = *(const float4*)(wp + 2 * GATES);
        float4 w3 = *(const float4*)(wp + 3 * GATES);
#pragma unroll
        for (int i = 0; i < 8; ++i) {
          float4 a4 = *(const float4*)&Ab[i * 600 + k4];
          gfma(acc[i], a4, w0, w1, w2, w3);
        }
      }
    }
    __syncthreads();  // Al reads done; red4 overlays it

    // ===== S5: deterministic 4-pass kh-reduction + LSTM + lazy c-commit =====
    {
      float4* red4 = (float4*)Al;
#pragma unroll
      for (int p = 0; p < 4; ++p) {
        red4[khG * 132 + boG * 64 + jjG * 2 + 0] = acc[2 * p];
        red4[khG * 132 + boG * 64 + jjG * 2 + 1] = acc[2 * p + 1];
        __syncthreads();
        if (tid < 128) {
          const int rb = tid >> 5, jjr = tid & 31;
          const int bo_r = rb >> 1, q_r = rb & 1;
          const int batch = bo_r * 8 + 2 * p + q_r;
          float4 g4 = make_float4(0.f, 0.f, 0.f, 0.f);
#pragma unroll
          for (int kh = 0; kh < 16; ++kh) {   // fixed order -> deterministic
            float4 v = red4[kh * 132 + bo_r * 64 + jjr * 2 + q_r];
            g4.x += v.x; g4.y += v.y; g4.z += v.z; g4.w += v.w;
          }
          const int jgr = csg * 32 + jjr;
          float4 bia = *(const float4*)&bf[(size_t)n * GATES + jgr * 4];
          float ig = sigf(g4.x + bia.x), fg = sigf(g4.y + bia.y);
          float gg = tanhf(g4.z + bia.z), og = sigf(g4.w + bia.w);
          float cc = c_cur[batch * 32 + jjr];
          if (t > 0) {
            float zn = zl[batch * 8 + n];
            int rank = 0;
#pragma unroll
            for (int j = 0; j < NB; ++j) {
              float zj = zl[batch * 8 + j];
              rank += (zj > zn || (zj == zn && j < n)) ? 1 : 0;
            }
            if (rank < TOPKN) cc = c_pend[batch * 32 + jjr];
          }
          float cn = fg * cc + ig * gg;
          float hn = og * tanhf(cn);
          c_cur[batch * 32 + jjr]  = cc;
          c_pend[batch * 32 + jjr] = cn;
          astore(&hnew[(size_t)(bg * 16 + batch) * NHID + n * BSZ + jgr], hn);
        }
        __syncthreads();
      }
    }
    gbar(flags, gen, 2u * t + 1u);

    // ===== PHASE B (WGs 0..63, one batch each) =====
    if (w < BS) {
      const int b = w;
      float* hnewl = Al;
      float* qcl   = Al + 2048;
      float* kcl   = Al + 3072;
      float* vcl   = Al + 4096;
      float* ocl   = Al + 5120;
      float* scl   = Al + 6144;   // [4][8][8]
      float* acl   = Al + 6400;   // [4][8][8]
      float* zlB   = Al + 6656;   // [8]

      for (int i = tid; i < NHID; i += 1024)
        hnewl[i] = aload(&hnew[(size_t)b * NHID + i]);
      if (tid >= 1016) zlB[tid - 1016] = aload(&zwr[b * 8 + (tid - 1016)]);
      __syncthreads();
      // qkv: tid<768 : (mat3, c4 32, kq 8) -> 8 nn accumulators, kq shfl-reduce
      if (tid < 768) {
        int mat = tid >> 8, c4 = (tid >> 3) & 31, kq = tid & 7;
        int c0 = c4 * 4;
        const float* W = (mat == 0) ? Wq_c : (mat == 1) ? Wk_c : Wv_c;
        float4 a8[8];
#pragma unroll
        for (int i = 0; i < 8; ++i) a8[i] = make_float4(0.f, 0.f, 0.f, 0.f);
#pragma unroll 2
        for (int m = 0; m < 8; ++m) {
          int d0 = kq * 4 + 32 * m;
          float4 w_0 = *(const float4*)&W[(size_t)(d0 + 0) * 128 + c0];
          float4 w_1 = *(const float4*)&W[(size_t)(d0 + 1) * 128 + c0];
          float4 w_2 = *(const float4*)&W[(size_t)(d0 + 2) * 128 + c0];
          float4 w_3 = *(const float4*)&W[(size_t)(d0 + 3) * 128 + c0];
#pragma unroll
          for (int nn = 0; nn < 8; ++nn) {
            float4 h4 = *(const float4*)&hnewl[nn * 256 + d0];
            sfma(a8[nn], h4.x, w_0); sfma(a8[nn], h4.y, w_1);
            sfma(a8[nn], h4.z, w_2); sfma(a8[nn], h4.w, w_3);
          }
        }
#pragma unroll
        for (int mk = 1; mk <= 4; mk <<= 1) {
#pragma unroll
          for (int nn = 0; nn < 8; ++nn) {
            a8[nn].x += __shfl_xor(a8[nn].x, mk);
            a8[nn].y += __shfl_xor(a8[nn].y, mk);
            a8[nn].z += __shfl_xor(a8[nn].z, mk);
            a8[nn].w += __shfl_xor(a8[nn].w, mk);
          }
        }
        if (kq == 0) {
          float* dst = (mat == 0) ? qcl : (mat == 1) ? kcl : vcl;
#pragma unroll
          for (int nn = 0; nn < 8; ++nn)
            *(float4*)&dst[nn * 128 + c0] = a8[nn];
        }
      }
      __syncthreads();
      // scores: tid<256 : (hh, nq, m) dot32
      if (tid < 256) {
        int hh = tid >> 6, nq = (tid >> 3) & 7, m = tid & 7;
        const float* qrow = &qcl[nq * 128 + hh * 32];
        const float* krow = &kcl[m * 128 + hh * 32];
        float a = 0.f;
#pragma unroll
        for (int k4 = 0; k4 < 8; ++k4) {
          float4 q4 = *(const float4*)&qrow[k4 * 4];
          float4 kv = *(const float4*)&krow[k4 * 4];
          a += q4.x * kv.x + q4.y * kv.y + q4.z * kv.z + q4.w * kv.w;
        }
        scl[tid] = a * 0.17677669529663687f;
      }
      __syncthreads();
      if (tid < 32) {  // softmax rows
        int hh = tid >> 3, nq = tid & 7;
        const float* row = &scl[hh * 64 + nq * 8];
        float mx = -1e30f;
#pragma unroll
        for (int m = 0; m < NB; ++m) mx = fmaxf(mx, row[m]);
        float e[NB]; float sum = 0.f;
#pragma unroll
        for (int m = 0; m < NB; ++m) { e[m] = expf(row[m] - mx); sum += e[m]; }
        float inv = 1.f / sum;
#pragma unroll
        for (int m = 0; m < NB; ++m) acl[(hh * 8 + nq) * 8 + m] = e[m] * inv;
      }
      __syncthreads();
      if (tid < 256) {  // oc = ac @ vc
        int nn = tid >> 5, c4 = tid & 31, c0 = c4 * 4, hh = c4 >> 3;
        const float* arow = &acl[(hh * 8 + nn) * 8];
        float4 a4 = make_float4(0.f, 0.f, 0.f, 0.f);
#pragma unroll
        for (int m = 0; m < NB; ++m) {
          float a = arow[m];
          float4 v4 = *(const float4*)&vcl[m * 128 + c0];
          sfma(a4, a, v4);
        }
        *(float4*)&ocl[tid * 4] = a4;
      }
      __syncthreads();
      if (tid < 512) {  // commit h (h_comm + global h for masked) + out
        int nn = tid >> 6, j0 = (tid & 63) * 4;
        int li = nn * BSZ + j0;
        float zn = zlB[nn];
        int rank = 0;
#pragma unroll
        for (int j = 0; j < NB; ++j) {
          float zj = zlB[j];
          rank += (zj > zn || (zj == zn && j < nn)) ? 1 : 0;
        }
        float4 hv4;
        if (rank < TOPKN) {
          const float* oc = &ocl[nn * 128];
          float4 add = make_float4(0.f, 0.f, 0.f, 0.f);
#pragma unroll 4
          for (int p = 0; p < 128; ++p) {
            float o = oc[p];
            float4 w4 = *(const float4*)&Wo_c[(size_t)p * BSZ + j0];
            sfma(add, o, w4);
          }
          hv4.x = hnewl[li] + add.x;     hv4.y = hnewl[li + 1] + add.y;
          hv4.z = hnewl[li + 2] + add.z; hv4.w = hnewl[li + 3] + add.w;
          *(float4*)&h_comm[li] = hv4;
          size_t base = (size_t)b * NHID + li;
          astore(&h[base], hv4.x);     astore(&h[base + 1], hv4.y);
          astore(&h[base + 2], hv4.z); astore(&h[base + 3], hv4.w);
        } else {
          hv4 = *(float4*)&h_comm[li];
        }
        *(float4*)&out[((size_t)t * BS + b) * NHID + li] = hv4;
      }
    }
    gbar(flags, gen, 2u * t + 2u);
  }
}

__global__ void k_sentinel(float* out) { out[0] = 12345.0f; }

extern "C" void kernel_launch(void* const* d_in, const int* in_sizes, int n_in,
                              void* d_out, int out_size, void* d_ws, size_t ws_size,
                              hipStream_t stream) {
  (void)in_sizes; (void)n_in; (void)out_size;
  const float* x      = (const float*)d_in[0];
  const float* h0     = (const float*)d_in[1];
  const float* c0     = (const float*)d_in[2];
  const float* W_enc  = (const float*)d_in[3];
  const float* b_enc  = (const float*)d_in[4];
  const float* Wq     = (const float*)d_in[5];
  const float* Wk     = (const float*)d_in[6];
  const float* Wv     = (const float*)d_in[7];
  const float* Wi     = (const float*)d_in[8];
  const float* Wh     = (const float*)d_in[9];
  const float* b_lstm = (const float*)d_in[10];
  const float* Wq_c   = (const float*)d_in[11];
  const float* Wk_c   = (const float*)d_in[12];
  const float* Wv_c   = (const float*)d_in[13];
  const float* Wo_c   = (const float*)d_in[14];
  float* out = (float*)d_out;

  float* ws = (float*)d_ws;
  size_t off = 0;
  auto alloc = [&](size_t nf) { float* p = ws + off; off += (nf + 15) & ~(size_t)15; return p; };
  float* k1v1 = alloc((size_t)T_STEPS * BS * RV);
  float* Wc   = alloc((size_t)NTOKEN * KV1);
  float* bias = alloc(KV1);
  float* Wf   = alloc((size_t)NB * KSUM * GATES);
  float* bf   = alloc((size_t)NB * GATES);
  float* h    = alloc((size_t)BS * NHID);
  float* hnew = alloc((size_t)BS * NHID);
  float* zbuf = alloc(2 * (size_t)BS * NB);
  // barrier: 256 flag lines + 256 gen lines (16 u32 each)
  unsigned* bar = (unsigned*)(ws + off); off += 8192 + 16;

  if (ws_size < off * sizeof(float)) {  // loud failure instead of OOB corruption
    hipLaunchKernelGGL(k_sentinel, dim3(1), dim3(1), 0, stream, out);
    return;
  }

  hipMemsetAsync(bar, 0, 8192 * sizeof(unsigned), stream);
  hipMemcpyAsync(h, h0, (size_t)BS * NHID * sizeof(float), hipMemcpyDeviceToDevice, stream);

  hipLaunchKernelGGL(k_wc,   dim3(NTOKEN + 1),       dim3(128), 0, stream, W_enc, b_enc, Wk, Wv, Wc, bias);
  hipLaunchKernelGGL(k_kv,   dim3(T_STEPS * BS / 8), dim3(256), 0, stream, x, Wc, bias, Wq, k1v1);
  hipLaunchKernelGGL(k_fuse, dim3(NB * KSUM),        dim3(256), 0, stream, Wi, Wh, b_lstm, Wf, bf);
  hipLaunchKernelGGL(k_rnn,  dim3(NWG),              dim3(1024), 0, stream,
                     k1v1, Wf, bf, Wq_c, Wk_c, Wv_c, Wo_c, c0,
                     h, hnew, zbuf, bar, out);
}